// Round 20
// baseline (6235.843 us; speedup 1.0000x reference)
//
#include <hip/hip_runtime.h>
#include <math.h>

// LSTM forward: T=1024, B=64, I=256, H=512 (4H=2048), fp32 in/out.
// Round 20: R19 + SPECULATIVE tagged gather.
//   R14-R19 established: step period = serial chain; last naked serial
//   element after spin-detect is the gather RTT. Fix: h travels as
//   uint2{packed bf16hi|lo, epoch}; consumers issue the gather right after
//   S2 + counter-add (overlaps x-window MFMA + spin), validate epochs
//   (EQUALITY vs t+1 -- poison/stale can't false-pass) after S3, and only
//   regather (guaranteed fresh: counter-after-drain) if stale. Late blocks
//   (which set the step period) skip the post-S3 gather entirely.
// grid 128 = 4 rg x 32 cg; block = 16 rows x 16 cells, 1024 thr, 16 waves.
// bf16-split MFMA (R13), W-frags in regs, linear staging (R14), drain on
// producer waves only + tid0-only counter spin (R14/R19-proven).

#define TT      1024
#define BB      64
#define II      256
#define HH      512
#define G4H     2048
#define RPB     16
#define NRG     4
#define NCG     32
#define THREADS 1024

typedef short  bf16x8 __attribute__((ext_vector_type(8)));
typedef float  f32x4  __attribute__((ext_vector_type(4)));

__device__ __forceinline__ unsigned int cvtpk_bf16(float a, float b) {
    unsigned int r;
    asm volatile("v_cvt_pk_bf16_f32 %0, %1, %2" : "=v"(r) : "v"(a), "v"(b));
    return r;   // lo16 = bf16(a), hi16 = bf16(b), RNE
}
__device__ __forceinline__ void coh_store_u2(uint2* p, uint2 v) {
    asm volatile("global_store_dwordx2 %0, %1, off sc0 sc1"
                 :: "v"(p), "v"(v) : "memory");
}
__device__ __forceinline__ float fast_tanh(float v) {
    const float e = __expf(-2.0f * fabsf(v));
    const float r = (1.0f - e) / (1.0f + e);
    return v < 0.0f ? -r : r;
}
__device__ __forceinline__ float sigm(float v) {
    return 1.0f / (1.0f + __expf(-v));
}

// convert 8 consecutive k-elements of one fragment into hi/lo bf16x8
__device__ __forceinline__ void cvt_frag(float4 v0, float4 v1,
                                         uint4& hi, uint4& lo) {
    hi.x = cvtpk_bf16(v0.x, v0.y);
    hi.y = cvtpk_bf16(v0.z, v0.w);
    hi.z = cvtpk_bf16(v1.x, v1.y);
    hi.w = cvtpk_bf16(v1.z, v1.w);
    lo.x = cvtpk_bf16(v0.x - __uint_as_float(hi.x << 16),
                      v0.y - __uint_as_float(hi.x & 0xffff0000u));
    lo.y = cvtpk_bf16(v0.z - __uint_as_float(hi.y << 16),
                      v0.w - __uint_as_float(hi.y & 0xffff0000u));
    lo.z = cvtpk_bf16(v1.x - __uint_as_float(hi.z << 16),
                      v1.y - __uint_as_float(hi.z & 0xffff0000u));
    lo.w = cvtpk_bf16(v1.z - __uint_as_float(hi.w << 16),
                      v1.w - __uint_as_float(hi.w & 0xffff0000u));
}

// unpack 8 packed u32 (hi16|lo16) -> fragment hi/lo words
__device__ __forceinline__ void unpack8(uint4 a, uint4 b,
                                        uint4& fh, uint4& fl) {
    fh.x = (a.x >> 16) | (a.y & 0xffff0000u);
    fh.y = (a.z >> 16) | (a.w & 0xffff0000u);
    fh.z = (b.x >> 16) | (b.y & 0xffff0000u);
    fh.w = (b.z >> 16) | (b.w & 0xffff0000u);
    fl.x = (a.x & 0xffffu) | (a.y << 16);
    fl.y = (a.z & 0xffffu) | (a.w << 16);
    fl.z = (b.x & 0xffffu) | (b.y << 16);
    fl.w = (b.z & 0xffffu) | (b.w << 16);
}

__global__ void init_ctr(unsigned int* c) { c[threadIdx.x] = 0; }

__global__ __launch_bounds__(THREADS) void lstm_persist(
    const float* __restrict__ x,    // [T][B][I]
    const float* __restrict__ Wi,   // [I][4H]
    const float* __restrict__ Wh,   // [H][4H]
    const float* __restrict__ bi,   // [4H]
    const float* __restrict__ bh,   // [4H]
    const float* __restrict__ h0p,  // [B][H]
    const float* __restrict__ c0p,  // [B][H]
    float* __restrict__ out,        // [T][B][H]
    uint2* __restrict__ hx,         // [2][64][512] (packed h, epoch)
    unsigned int* __restrict__ ctr) // [NRG*32], zeroed
{
    const int tid   = threadIdx.x;
    const int cg    = blockIdx.x & 31;
    const int rg    = blockIdx.x >> 5;
    const int row0  = rg * RPB;
    const int cell0 = cg * 16;
    const int wv    = tid >> 6;           // 0..15
    const int lane  = tid & 63;
    const int n4    = wv >> 2;            // gate 0..3 (N-tile)
    const int k4    = wv & 3;             // K-chunk 0..3

    __shared__ uint4 aFH[24 * 64];
    __shared__ uint4 aFL[24 * 64];
    __shared__ float red[16 * 64 * 4];
    __shared__ float c_lds[RPB][16];

    const int s_ls = tid & 63;
    const int s_r  = s_ls & 15;
    const int s_k2 = ((s_ls >> 4) & 3) * 8;
    const int xkk  = tid >> 6;
    const int hkc  = (tid >> 6) * 32 + s_k2;

    // ---- one-time: W fragments -> registers ----
    bf16x8 wH[6], wL[6];
    {
        const int J = n4 * HH + cell0 + (lane & 15);
        #pragma unroll
        for (int s = 0; s < 6; ++s) {
            const int kk = (s < 2) ? (k4 * 2 + s) : (8 + k4 * 4 + (s - 2));
            const int kb = kk * 32 + (lane >> 4) * 8;
            float w[8];
            #pragma unroll
            for (int e = 0; e < 8; ++e) {
                const int k = kb + e;
                w[e] = (k < II) ? Wi[(size_t)k * G4H + J]
                                : Wh[(size_t)(k - II) * G4H + J];
            }
            uint4 hi, lo;
            cvt_frag(make_float4(w[0], w[1], w[2], w[3]),
                     make_float4(w[4], w[5], w[6], w[7]), hi, lo);
            wH[s] = *(bf16x8*)&hi;
            wL[s] = *(bf16x8*)&lo;
        }
    }

    // ---- update-role constants (threads 0..255) ----
    float b4[4];
    if (tid < 256) {
        const int r = tid >> 4, m = tid & 15;
        #pragma unroll
        for (int g = 0; g < 4; ++g)
            b4[g] = bi[g * HH + cell0 + m] + bh[g * HH + cell0 + m];
        c_lds[r][m] = c0p[(size_t)(row0 + r) * HH + cell0 + m];
    }

    // ---- prologue: stage x_0 (tid<512) and h0 (all) fragments ----
    if (tid < 512) {
        const float* xr = x + (size_t)(row0 + s_r) * II + xkk * 32 + s_k2;
        uint4 hi, lo;
        cvt_frag(*(const float4*)xr, *(const float4*)(xr + 4), hi, lo);
        aFH[tid] = hi; aFL[tid] = lo;
    }
    {
        const float* hr = h0p + (size_t)(row0 + s_r) * HH + hkc;
        uint4 hi, lo;
        cvt_frag(*(const float4*)hr, *(const float4*)(hr + 4), hi, lo);
        aFH[512 + tid] = hi; aFL[512 + tid] = lo;
    }
    __syncthreads();

    // ---- x-MFMA for t=0 ----
    f32x4 acc = {0.f, 0.f, 0.f, 0.f};
    #pragma unroll
    for (int q = 0; q < 2; ++q) {
        const int kk = k4 * 2 + q;
        const bf16x8 ah = *(const bf16x8*)&aFH[kk * 64 + lane];
        const bf16x8 al = *(const bf16x8*)&aFL[kk * 64 + lane];
        acc = __builtin_amdgcn_mfma_f32_16x16x32_bf16(ah, wH[q], acc, 0, 0, 0);
        acc = __builtin_amdgcn_mfma_f32_16x16x32_bf16(ah, wL[q], acc, 0, 0, 0);
        acc = __builtin_amdgcn_mfma_f32_16x16x32_bf16(al, wH[q], acc, 0, 0, 0);
    }

    unsigned int* myctr = ctr + rg * 32;

    for (int t = 0; t < TT; ++t) {
        const bool more = (t + 1 < TT);

        // ---- issue x_{t+1} loads early (tid<512) ----
        float4 xv0, xv1;
        if (more && tid < 512) {
            const float* xr = x + ((size_t)(t + 1) * BB + row0 + s_r) * II
                              + xkk * 32 + s_k2;
            xv0 = *(const float4*)xr;
            xv1 = *(const float4*)(xr + 4);
        }

        // ---- h-MFMA, acc carries x part ----
        #pragma unroll
        for (int q = 0; q < 4; ++q) {
            const int kk = 8 + k4 * 4 + q;
            const bf16x8 ah = *(const bf16x8*)&aFH[kk * 64 + lane];
            const bf16x8 al = *(const bf16x8*)&aFL[kk * 64 + lane];
            acc = __builtin_amdgcn_mfma_f32_16x16x32_bf16(ah, wH[2 + q], acc, 0, 0, 0);
            acc = __builtin_amdgcn_mfma_f32_16x16x32_bf16(ah, wL[2 + q], acc, 0, 0, 0);
            acc = __builtin_amdgcn_mfma_f32_16x16x32_bf16(al, wH[2 + q], acc, 0, 0, 0);
        }

        // ---- publish C partial; stage x_{t+1} (tid<512) ----
        ((f32x4*)red)[wv * 64 + lane] = acc;
        if (more && tid < 512) {
            uint4 hi, lo;
            cvt_frag(xv0, xv1, hi, lo);
            aFH[tid] = hi; aFL[tid] = lo;
        }
        __syncthreads();                        // S1

        // ---- cell update (threads 0..255): out (plain) + hx (tagged) ----
        if (tid < 256) {
            const int r = tid >> 4, m = tid & 15;
            const int lc  = m + 16 * (r >> 2);
            const int reg = r & 3;
            float g4[4];
            #pragma unroll
            for (int g = 0; g < 4; ++g) {
                float s = b4[g];
                #pragma unroll
                for (int p = 0; p < 4; ++p)
                    s += red[((g * 4 + p) * 64 + lc) * 4 + reg];
                g4[g] = s;
            }
            const float ig = sigm(g4[0]);
            const float fg = sigm(g4[1]);
            const float gg = fast_tanh(g4[2]);
            const float og = sigm(g4[3]);
            const float cn = fg * c_lds[r][m] + ig * gg;
            c_lds[r][m] = cn;
            const float hv = og * fast_tanh(cn);
            out[((size_t)t * BB + row0 + r) * HH + cell0 + m] = hv;   // plain
            if (more) {
                const unsigned int hb16 = cvtpk_bf16(hv, hv) & 0xffffu;
                const float hf = __uint_as_float(hb16 << 16);
                const unsigned int lb16 = cvtpk_bf16(hv - hf, hv - hf) & 0xffffu;
                uint2 pr;
                pr.x = (hb16 << 16) | lb16;
                pr.y = (unsigned int)(t + 1);
                coh_store_u2(&hx[((size_t)(t & 1) * BB + row0 + r) * HH
                                 + cell0 + m], pr);
            }
        }

        // ---- drain: producer waves (0..3) only ----
        if (wv < 4) asm volatile("s_waitcnt vmcnt(0) lgkmcnt(0)" ::: "memory");
        __syncthreads();                        // S2
        if (more) {
            if (tid == 0)
                __hip_atomic_fetch_add(myctr, 1u, __ATOMIC_RELAXED,
                                       __HIP_MEMORY_SCOPE_AGENT);

            // ---- SPECULATIVE gather: 8 tagged u64, issued before MFMA ----
            const unsigned long long* hb8 = (const unsigned long long*)
                (hx + ((size_t)(t & 1) * BB + row0 + s_r) * HH + hkc);
            unsigned long long g[8];
            #pragma unroll
            for (int i = 0; i < 8; ++i)
                g[i] = __hip_atomic_load(hb8 + i, __ATOMIC_RELAXED,
                                         __HIP_MEMORY_SCOPE_AGENT);

            // ---- x-window MFMA (overlaps the gather RTT + spin) ----
            acc = (f32x4){0.f, 0.f, 0.f, 0.f};
            #pragma unroll
            for (int q = 0; q < 2; ++q) {
                const int kk = k4 * 2 + q;
                const bf16x8 ah = *(const bf16x8*)&aFH[kk * 64 + lane];
                const bf16x8 al = *(const bf16x8*)&aFL[kk * 64 + lane];
                acc = __builtin_amdgcn_mfma_f32_16x16x32_bf16(ah, wH[q], acc, 0, 0, 0);
                acc = __builtin_amdgcn_mfma_f32_16x16x32_bf16(ah, wL[q], acc, 0, 0, 0);
                acc = __builtin_amdgcn_mfma_f32_16x16x32_bf16(al, wH[q], acc, 0, 0, 0);
            }

            // ---- epoch validation (EQUALITY: poison can't false-pass) ----
            const unsigned int tgt = (unsigned int)(t + 1);
            bool ok = true;
            #pragma unroll
            for (int i = 0; i < 8; ++i)
                ok &= ((unsigned int)(g[i] >> 32) == tgt);

            // ---- tid0-only spin (guarantee point) ----
            if (tid == 0) {
                const unsigned int target = 32u * tgt;
                while (__hip_atomic_load(myctr, __ATOMIC_RELAXED,
                                         __HIP_MEMORY_SCOPE_AGENT) < target) {
                    __builtin_amdgcn_s_sleep(1);
                }
            }
            __syncthreads();                    // S3

            // ---- extract packed values; regather only if speculation stale ----
            unsigned int v0 = (unsigned int)g[0], v1 = (unsigned int)g[1],
                         v2 = (unsigned int)g[2], v3 = (unsigned int)g[3],
                         v4 = (unsigned int)g[4], v5 = (unsigned int)g[5],
                         v6 = (unsigned int)g[6], v7 = (unsigned int)g[7];
            if (!ok) {                          // guaranteed fresh post-spin
                uint4 r0, r1, r2, r3;
                asm volatile(
                    "global_load_dwordx4 %0, %4, off sc0 sc1\n\t"
                    "global_load_dwordx4 %1, %4, off offset:16 sc0 sc1\n\t"
                    "global_load_dwordx4 %2, %4, off offset:32 sc0 sc1\n\t"
                    "global_load_dwordx4 %3, %4, off offset:48 sc0 sc1\n\t"
                    "s_waitcnt vmcnt(0)"
                    : "=&v"(r0), "=&v"(r1), "=&v"(r2), "=&v"(r3)
                    : "v"(hb8)
                    : "memory");
                v0 = r0.x; v1 = r0.z; v2 = r1.x; v3 = r1.z;
                v4 = r2.x; v5 = r2.z; v6 = r3.x; v7 = r3.z;
            }

            // ---- unpack -> fragment hi/lo, stage (linear writes) ----
            {
                uint4 a4 = {v0, v1, v2, v3};
                uint4 b4v = {v4, v5, v6, v7};
                uint4 fh, fl;
                unpack8(a4, b4v, fh, fl);
                aFH[512 + tid] = fh; aFL[512 + tid] = fl;
            }
            __syncthreads();                    // S4
        }
    }
}

extern "C" void kernel_launch(void* const* d_in, const int* in_sizes, int n_in,
                              void* d_out, int out_size, void* d_ws, size_t ws_size,
                              hipStream_t stream) {
    const float* x  = (const float*)d_in[0];
    const float* Wi = (const float*)d_in[1];
    const float* Wh = (const float*)d_in[2];
    const float* bi = (const float*)d_in[3];
    const float* bh = (const float*)d_in[4];
    const float* h0 = (const float*)d_in[5];
    const float* c0 = (const float*)d_in[6];
    float* out = (float*)d_out;

    uint2* hx = (uint2*)d_ws;                              // 512 KB
    unsigned int* ctr = (unsigned int*)((char*)d_ws + 2 * BB * HH * 8);

    init_ctr<<<1, 128, 0, stream>>>(ctr);

    void* args[] = { (void*)&x, (void*)&Wi, (void*)&Wh, (void*)&bi,
                     (void*)&bh, (void*)&h0, (void*)&c0, (void*)&out,
                     (void*)&hx, (void*)&ctr };
    hipError_t e = hipLaunchCooperativeKernel((const void*)lstm_persist,
                                              dim3(NRG * NCG), dim3(THREADS),
                                              args, 0, stream);
    if (e != hipSuccess) {
        (void)hipGetLastError();
        lstm_persist<<<dim3(NRG * NCG), dim3(THREADS), 0, stream>>>(
            x, Wi, Wh, bi, bh, h0, c0, out, hx, ctr);
    }
}